// Round 7
// baseline (641.816 us; speedup 1.0000x reference)
//
#include <hip/hip_runtime.h>
#include <hip/hip_bf16.h>
#include <stdint.h>

typedef __hip_bfloat16 bf16;
typedef __attribute__((ext_vector_type(8))) short short8;
typedef __attribute__((ext_vector_type(4))) short short4_t;
typedef __attribute__((ext_vector_type(4))) float float4_t;

__device__ __forceinline__ short f2b_bits(float f) {
  union { float f; unsigned u; } v; v.f = f;
  unsigned r = (v.u + 0x7FFF + ((v.u >> 16) & 1)) >> 16;  // RNE
  return (short)r;
}
__device__ __forceinline__ bf16 f2b(float f) {
  short s = f2b_bits(f);
  bf16 h; __builtin_memcpy(&h, &s, 2);
  return h;
}
// load element idx from p (fp32 if f32 else bf16) -> bf16
__device__ __forceinline__ bf16 ld_bf16(const void* p, size_t idx, int f32) {
  if (f32) return f2b(((const float*)p)[idx]);
  return ((const bf16*)p)[idx];
}

// async global->LDS, 16B per lane. LDS dest must be wave-uniform base + lane*16.
__device__ __forceinline__ void gload_lds16(const void* g, void* l) {
  __builtin_amdgcn_global_load_lds(
      (const __attribute__((address_space(1))) void*)g,
      (__attribute__((address_space(3))) void*)l, 16, 0, 0);
}

// ---------- dtype detector: probe = bi (1024 elements) ----------
__global__ void detect_dtype(const void* probe, int* flag) {
  int lane = threadIdx.x;  // 64 threads
  const unsigned short* u = (const unsigned short*)probe;
  const float* fp = (const float*)probe;
  int cb = 0, cf = 0;
  for (int j = lane; j < 256; j += 64) {
    unsigned short he = u[2 * j];
    int e = (he >> 7) & 0xFF;
    cb += (e >= 0x60 && e <= 0x7E);
    float af = fabsf(fp[j]);
    cf += (af > 1e-9f && af < 1.0f);
  }
#pragma unroll
  for (int off = 32; off > 0; off >>= 1) {
    cb += __shfl_down(cb, off);
    cf += __shfl_down(cf, off);
  }
  if (lane == 0) *flag = (cf > cb) ? 1 : 0;  // 1 = inputs are fp32
}

// ---------- all 4 weight transposes in ONE launch (range-decoded) ----------
// dst[n*K+k] = src[k*N+n]; K,N multiples of 64.
__global__ __launch_bounds__(256) void transpose_all(
    const void* __restrict__ Wi, const void* __restrict__ Wb,
    const void* __restrict__ Wf, const void* __restrict__ Wo,
    bf16* __restrict__ WiT, bf16* __restrict__ WbfT2, bf16* __restrict__ WoT,
    const int* __restrict__ flagp)
{
  const int f32 = *flagp;
  int b = blockIdx.x;
  const void* src; bf16* dst; int K, N, tb;
  if (b < 1024)      { src = Wi; dst = WiT;              K = 4096; N = 1024; tb = b; }
  else if (b < 1152) { src = Wb; dst = WbfT2;            K = 1024; N = 512;  tb = b - 1024; }
  else if (b < 1280) { src = Wf; dst = WbfT2 + 512*1024; K = 1024; N = 512;  tb = b - 1152; }
  else               { src = Wo; dst = WoT;              K = 128;  N = 4096; tb = b - 1280; }
  int nbk = K >> 6;
  int kb = (tb % nbk) * 64, nb = (tb / nbk) * 64;
  __shared__ bf16 tile[64][65];
  int tx = threadIdx.x & 63;
  int ty = threadIdx.x >> 6;  // 0..3
#pragma unroll
  for (int i = 0; i < 64; i += 4)
    tile[ty + i][tx] = ld_bf16(src, (size_t)(kb + ty + i) * N + nb + tx, f32);
  __syncthreads();
#pragma unroll
  for (int i = 0; i < 64; i += 4)
    dst[(size_t)(nb + ty + i) * K + kb + tx] = tile[tx][ty + i];
}

// ---------- small conversions + Ww fused into WbfT2 rows 1024..1151 ----------
__global__ __launch_bounds__(256) void cvt_small(
    const void* __restrict__ Ww, const void* __restrict__ bw,
    const void* __restrict__ bi, const void* __restrict__ bb,
    const void* __restrict__ bf_, const void* __restrict__ bo,
    bf16* __restrict__ WbfT2, bf16* __restrict__ bbf2,
    bf16* __restrict__ biC, bf16* __restrict__ boC,
    const int* __restrict__ flagp)
{
  const int f32 = *flagp;
  int i = blockIdx.x * 256 + threadIdx.x;  // grid 512 -> 131072 threads
  if (i < 131072) {
    int r = i >> 10, k = i & 1023;
    bf16 v = (r < 8) ? ld_bf16(Ww, (size_t)k * 8 + r, f32) : f2b(0.f);
    WbfT2[(size_t)(1024 + r) * 1024 + k] = v;
  }
  if (i < 128) bbf2[1024 + i] = (i < 8) ? ld_bf16(bw, i, f32) : f2b(0.f);
  if (i < 1024) biC[i] = ld_bf16(bi, i, f32);
  if (i < 512)  bbf2[i] = ld_bf16(bb, i, f32);
  if (i < 512)  bbf2[512 + i] = ld_bf16(bf_, i, f32);
  if (i < 4096) boC[i] = ld_bf16(bo, i, f32);
}

// ---------- MFMA GEMM core: C = A(MxK) * BT(NxK)^T + bias [+resid] ----------
// 64x128 tile, BK=64, 4 waves (2x2), single-buffered 2-barrier loop.
// Tile ladder measured on THIS problem (GEMM1, M=8192 N=1024 K=4096):
//   128^2/512blk -> 254 TF (R1) | 128^2 splitk/3-res -> 292 TF (R4)
//   64x128/1024blk -> 404 TF (R2/R5, best) | 64x64/2048blk -> 258 TF +
//   3.5x FETCH blowup from lost A-reuse (R6). Tile dim is a closed axis.
// Epilogue: LDS-staged coalesced finalize (scattered per-lane 4B/2B
// stores -> float4/short4 full-coalesced; reuses the 24KB staging smem).
template <int BM, int BN>
__device__ __forceinline__ void gemm_core(
    const void* __restrict__ A,      // M x K (bf16, or fp32 if *aF32)
    const bf16* __restrict__ BT,     // N x K
    const bf16* __restrict__ bias,   // N
    const void* __restrict__ resid,  // M x N (nullable; dtype follows rF32)
    void* __restrict__ C,            // M x N (bf16, or fp32 if *cF32)
    const int* __restrict__ aF32, const int* __restrict__ rF32,
    const int* __restrict__ cF32,
    int M, int N, int K, int clip_cols)
{
  static_assert(BM == 64 && BN == 128, "epilogue assumes 64x128");
  constexpr int FM = BM / 32;  // 2
  constexpr int FN = BN / 32;  // 4
  __shared__ alignas(16) char smem[(BM + BN) * 64 * 2];  // 24576 B
  bf16* As = (bf16*)smem;            // BM*64
  bf16* Bs = (bf16*)smem + BM * 64;  // BN*64
  const int af32 = aF32 ? *aF32 : 0;
  const int rf32 = rF32 ? *rF32 : 0;
  const int cf32 = cF32 ? *cF32 : 0;
  const int tid  = threadIdx.x;
  const int wave = tid >> 6;
  const int lane = tid & 63;
  const int m0 = blockIdx.x * BM;
  const int n0 = blockIdx.y * BN;
  const int wm = (wave >> 1) * (BM / 2);
  const int wn = (wave & 1) * (BN / 2);
  const int lm = lane & 15;
  const int lk = (lane >> 4) * 8;

  float4_t acc[FM][FN];
#pragma unroll
  for (int i = 0; i < FM; i++)
#pragma unroll
    for (int j = 0; j < FN; j++) acc[i][j] = (float4_t){0.f, 0.f, 0.f, 0.f};

  for (int k0 = 0; k0 < K; k0 += 64) {
    // B tile: BN rows x 64 cols, async direct-to-LDS (always bf16)
#pragma unroll
    for (int i = 0; i < BN / 32; i++) {
      int V = tid + 256 * i;
      int row = V >> 3;
      int kc  = (V & 7) * 8;
      gload_lds16(BT + (size_t)(n0 + row) * K + k0 + kc, Bs + (size_t)V * 8);
    }
    // A tile: BM rows x 64 cols
#pragma unroll
    for (int i = 0; i < BM / 32; i++) {
      int V = tid + 256 * i;
      int row = V >> 3;
      int kc  = (V & 7) * 8;
      if (af32) {
        const float* ap = (const float*)A + (size_t)(m0 + row) * K + k0 + kc;
        float4_t f0 = *(const float4_t*)ap;
        float4_t f1 = *(const float4_t*)(ap + 4);
        short8 v;
        v[0] = f2b_bits(f0[0]); v[1] = f2b_bits(f0[1]);
        v[2] = f2b_bits(f0[2]); v[3] = f2b_bits(f0[3]);
        v[4] = f2b_bits(f1[0]); v[5] = f2b_bits(f1[1]);
        v[6] = f2b_bits(f1[2]); v[7] = f2b_bits(f1[3]);
        *(short8*)(As + (size_t)V * 8) = v;
      } else {
        gload_lds16((const bf16*)A + (size_t)(m0 + row) * K + k0 + kc,
                    As + (size_t)V * 8);
      }
    }
    __syncthreads();
#pragma unroll
    for (int kk = 0; kk < 64; kk += 32) {
      short8 af[FM], bfr[FN];
#pragma unroll
      for (int mi = 0; mi < FM; mi++)
        af[mi] = *(const short8*)(As + (wm + mi * 16 + lm) * 64 + kk + lk);
#pragma unroll
      for (int ni = 0; ni < FN; ni++)
        bfr[ni] = *(const short8*)(Bs + (wn + ni * 16 + lm) * 64 + kk + lk);
#pragma unroll
      for (int mi = 0; mi < FM; mi++)
#pragma unroll
        for (int ni = 0; ni < FN; ni++)
          acc[mi][ni] = __builtin_amdgcn_mfma_f32_16x16x32_bf16(
              af[mi], bfr[ni], acc[mi][ni], 0, 0, 0);
    }
    __syncthreads();
  }

  // ---- coalesced epilogue: per 64-col half, stage fp32 tile in LDS ----
  // MFMA C/D layout: col=lane&15, row=(lane>>4)*4+r.
  float* EP = (float*)smem;           // [64][68] fp32 = 17408 B <= 24576
  const int ep_r  = tid >> 2;         // 0..63 (row of tile)
  const int ep_c0 = (tid & 3) * 16;   // 0/16/32/48 (col chunk)
#pragma unroll
  for (int h = 0; h < 2; h++) {
    if ((wn >> 6) == h) {             // this wave's cols are in half h
#pragma unroll
      for (int mi = 0; mi < FM; mi++)
#pragma unroll
        for (int ni = 0; ni < FN; ni++) {
          int cl = (wn - h * 64) + ni * 16 + lm;  // 0..63
#pragma unroll
          for (int r = 0; r < 4; r++) {
            int rw = wm + mi * 16 + (lane >> 4) * 4 + r;  // 0..63
            EP[rw * 68 + cl] = acc[mi][ni][r];
          }
        }
    }
    __syncthreads();
    {
      int gr = m0 + ep_r;
      int gcb = n0 + h * 64 + ep_c0;
#pragma unroll
      for (int c4 = 0; c4 < 4; c4++) {
        float4_t v = *(const float4_t*)(EP + ep_r * 68 + ep_c0 + c4 * 4);
        int col = gcb + c4 * 4;
        size_t idx = (size_t)gr * N + col;
        float o[4];
#pragma unroll
        for (int j = 0; j < 4; j++) {
          float t = v[j] + __bfloat162float(bias[col + j]);
          if (col + j < clip_cols) t = fminf(fmaxf(t, -10.f), 10.f);
          o[j] = t;
        }
        if (resid) {
          if (rf32) {
            float4_t rv = *(const float4_t*)((const float*)resid + idx);
#pragma unroll
            for (int j = 0; j < 4; j++) o[j] += rv[j];
          } else {
            short4_t rv = *(const short4_t*)((const bf16*)resid + idx);
#pragma unroll
            for (int j = 0; j < 4; j++) {
              bf16 hb; short sb = rv[j]; __builtin_memcpy(&hb, &sb, 2);
              o[j] += __bfloat162float(hb);
            }
          }
        }
        if (cf32) {
          *(float4_t*)((float*)C + idx) = (float4_t){o[0], o[1], o[2], o[3]};
        } else {
          short4_t pv;
#pragma unroll
          for (int j = 0; j < 4; j++) pv[j] = f2b_bits(o[j]);
          *(short4_t*)((bf16*)C + idx) = pv;
        }
      }
    }
    __syncthreads();  // EP reads done before next half overwrites
  }
}

// distinct names -> per-GEMM rocprof attribution
__global__ __launch_bounds__(256) void gemm_x(
    const void* A, const bf16* BT, const bf16* bias, const void* resid,
    void* C, const int* aF32, const int* rF32, const int* cF32,
    int M, int N, int K, int clip_cols) {
  gemm_core<64, 128>(A, BT, bias, resid, C, aF32, rF32, cF32, M, N, K, clip_cols);
}
__global__ __launch_bounds__(256) void gemm_h(
    const void* A, const bf16* BT, const bf16* bias, const void* resid,
    void* C, const int* aF32, const int* rF32, const int* cF32,
    int M, int N, int K, int clip_cols) {
  gemm_core<64, 128>(A, BT, bias, resid, C, aF32, rF32, cF32, M, N, K, clip_cols);
}
__global__ __launch_bounds__(256) void gemm_o(
    const void* A, const bf16* BT, const bf16* bias, const void* resid,
    void* C, const int* aF32, const int* rF32, const int* cF32,
    int M, int N, int K, int clip_cols) {
  gemm_core<64, 128>(A, BT, bias, resid, C, aF32, rF32, cF32, M, N, K, clip_cols);
}

// ---------- per-token: softmax over fused logit cols + temporal mix + agg ----
__global__ __launch_bounds__(128) void build_combined(
    const bf16* __restrict__ bcfs,  // 8192 x 1152: 0..511 bc, 512..1023 fs, 1024..1031 logits
    bf16* __restrict__ comb)        // 8192 x 128
{
  int t = blockIdx.x;
  int tid = threadIdx.x;  // 0..127
  int tl = t & 2047;      // t_local within batch (T=2048)
  __shared__ float lg[8];
  __shared__ float w[8];
  if (tid < 8) lg[tid] = __bfloat162float(bcfs[(size_t)t * 1152 + 1024 + tid]);
  __syncthreads();
  if (tid < 8) {
    float mx = lg[0];
#pragma unroll
    for (int i = 1; i < 8; i++) mx = fmaxf(mx, lg[i]);
    float den = 0.f;
#pragma unroll
    for (int i = 0; i < 8; i++) den += expf(lg[i] - mx);
    w[tid] = expf(lg[tid] - mx) / den;
  }
  __syncthreads();
  float s = 0.f;
  if (tid < 64) {
    int d = tid;
    const bf16* bc = bcfs + (size_t)t * 1152;
    size_t tp = (tl == 0) ? (size_t)t : (size_t)t - 1;
    const bf16* bp = bcfs + tp * 1152;
#pragma unroll
    for (int p = 0; p < 8; p++) {
      float cur = __bfloat162float(bc[p * 64 + d]);
      float v = (tl == 0) ? cur : (0.9f * cur + 0.1f * __bfloat162float(bp[p * 64 + d]));
      s += w[p] * v;
    }
  } else {
    int d = tid - 64;
    const bf16* fsrow = bcfs + (size_t)t * 1152 + 512;
#pragma unroll
    for (int p = 0; p < 8; p++) s += w[p] * __bfloat162float(fsrow[p * 64 + d]);
  }
  comb[(size_t)t * 128 + tid] = __float2bfloat16(s);
}

extern "C" void kernel_launch(void* const* d_in, const int* in_sizes, int n_in,
                              void* d_out, int out_size, void* d_ws, size_t ws_size,
                              hipStream_t stream) {
  (void)in_sizes; (void)n_in; (void)out_size; (void)ws_size;
  const void* x   = d_in[0];   // 8192 x 4096
  const void* Wi  = d_in[1];   // 4096 x 1024
  const void* bi  = d_in[2];   // 1024
  const void* Wb  = d_in[3];   // 1024 x 512
  const void* bb  = d_in[4];   // 512
  const void* Wf  = d_in[5];   // 1024 x 512
  const void* bfv = d_in[6];   // 512
  const void* Ww  = d_in[9];   // 1024 x 8
  const void* bw  = d_in[10];  // 8
  const void* Wo  = d_in[17];  // 128 x 4096
  const void* bo  = d_in[18];  // 4096

  char* ws = (char*)d_ws;
  bf16*  h_bot = (bf16*)(ws + 0);          // 16,777,216 (comb aliases after GEMM2)
  bf16*  comb  = (bf16*)(ws + 0);          // 2,097,152 alias: h_bot dead after GEMM2
  bf16*  bcfs  = (bf16*)(ws + 16777216);   // 8192x1152x2 = 18,874,368
  bf16*  WiT   = (bf16*)(ws + 35651584);   //  8,388,608
  bf16*  WbfT2 = (bf16*)(ws + 44040192);   // 1152x1024x2 = 2,359,296
  bf16*  WoT   = (bf16*)(ws + 46399488);   //  1,048,576
  bf16*  biC   = (bf16*)(ws + 47448064);   //      2,048
  bf16*  bbf2C = (bf16*)(ws + 47450112);   //      2,304
  bf16*  boC   = (bf16*)(ws + 47452416);   //      8,192
  int*   flag  = (int*)(ws + 47460608);    //          4

  detect_dtype<<<1, 64, 0, stream>>>(bi, flag);

  transpose_all<<<1408, 256, 0, stream>>>(Wi, Wb, Wf, Wo, WiT, WbfT2, WoT, flag);
  cvt_small<<<512, 256, 0, stream>>>(Ww, bw, bi, bb, bfv, bo,
                                     WbfT2, bbf2C, biC, boC, flag);

  // GEMM1: h_bot = x @ Wi + bi  (A = x fp32-flagged; 64x128, grid 1024)
  gemm_x<<<dim3(128, 8), 256, 0, stream>>>(
      x, WiT, biC, nullptr, h_bot, flag, nullptr, nullptr,
      8192, 1024, 4096, 0);
  // GEMM2: [bc | fs | logits | pad] = h_bot @ [Wb|Wf|Ww|0] + [bb|bf|bw|0]
  gemm_h<<<dim3(128, 9), 256, 0, stream>>>(
      h_bot, WbfT2, bbf2C, nullptr, bcfs, nullptr, nullptr, nullptr,
      8192, 1152, 1024, 512);
  build_combined<<<8192, 128, 0, stream>>>(bcfs, comb);
  // GEMM3: out = x + comb @ Wo + bo — resid = x (flagged), OUTPUT dtype follows flag
  gemm_o<<<dim3(128, 32), 256, 0, stream>>>(
      comb, WoT, boC, x, d_out, nullptr, flag, flag,
      8192, 4096, 128, 0);
}

// Round 8
// 507.579 us; speedup vs baseline: 1.2645x; 1.2645x over previous
//
#include <hip/hip_runtime.h>
#include <hip/hip_bf16.h>
#include <stdint.h>

typedef __hip_bfloat16 bf16;
typedef __attribute__((ext_vector_type(8))) short short8;
typedef __attribute__((ext_vector_type(4))) short short4_t;
typedef __attribute__((ext_vector_type(4))) float float4_t;

__device__ __forceinline__ short f2b_bits(float f) {
  union { float f; unsigned u; } v; v.f = f;
  unsigned r = (v.u + 0x7FFF + ((v.u >> 16) & 1)) >> 16;  // RNE
  return (short)r;
}
__device__ __forceinline__ bf16 f2b(float f) {
  short s = f2b_bits(f);
  bf16 h; __builtin_memcpy(&h, &s, 2);
  return h;
}
// load element idx from p (fp32 if f32 else bf16) -> bf16
__device__ __forceinline__ bf16 ld_bf16(const void* p, size_t idx, int f32) {
  if (f32) return f2b(((const float*)p)[idx]);
  return ((const bf16*)p)[idx];
}

// async global->LDS, 16B per lane. LDS dest must be wave-uniform base + lane*16.
__device__ __forceinline__ void gload_lds16(const void* g, void* l) {
  __builtin_amdgcn_global_load_lds(
      (const __attribute__((address_space(1))) void*)g,
      (__attribute__((address_space(3))) void*)l, 16, 0, 0);
}

// ---------- dtype detector: probe = bi (1024 elements) ----------
__global__ void detect_dtype(const void* probe, int* flag) {
  int lane = threadIdx.x;  // 64 threads
  const unsigned short* u = (const unsigned short*)probe;
  const float* fp = (const float*)probe;
  int cb = 0, cf = 0;
  for (int j = lane; j < 256; j += 64) {
    unsigned short he = u[2 * j];
    int e = (he >> 7) & 0xFF;
    cb += (e >= 0x60 && e <= 0x7E);
    float af = fabsf(fp[j]);
    cf += (af > 1e-9f && af < 1.0f);
  }
#pragma unroll
  for (int off = 32; off > 0; off >>= 1) {
    cb += __shfl_down(cb, off);
    cf += __shfl_down(cf, off);
  }
  if (lane == 0) *flag = (cf > cb) ? 1 : 0;  // 1 = inputs are fp32
}

// ---------- all 4 weight transposes in ONE launch (range-decoded) ----------
// dst[n*K+k] = src[k*N+n]; K,N multiples of 64.
__global__ __launch_bounds__(256) void transpose_all(
    const void* __restrict__ Wi, const void* __restrict__ Wb,
    const void* __restrict__ Wf, const void* __restrict__ Wo,
    bf16* __restrict__ WiT, bf16* __restrict__ WbfT2, bf16* __restrict__ WoT,
    const int* __restrict__ flagp)
{
  const int f32 = *flagp;
  int b = blockIdx.x;
  const void* src; bf16* dst; int K, N, tb;
  if (b < 1024)      { src = Wi; dst = WiT;              K = 4096; N = 1024; tb = b; }
  else if (b < 1152) { src = Wb; dst = WbfT2;            K = 1024; N = 512;  tb = b - 1024; }
  else if (b < 1280) { src = Wf; dst = WbfT2 + 512*1024; K = 1024; N = 512;  tb = b - 1152; }
  else               { src = Wo; dst = WoT;              K = 128;  N = 4096; tb = b - 1280; }
  int nbk = K >> 6;
  int kb = (tb % nbk) * 64, nb = (tb / nbk) * 64;
  __shared__ bf16 tile[64][65];
  int tx = threadIdx.x & 63;
  int ty = threadIdx.x >> 6;  // 0..3
#pragma unroll
  for (int i = 0; i < 64; i += 4)
    tile[ty + i][tx] = ld_bf16(src, (size_t)(kb + ty + i) * N + nb + tx, f32);
  __syncthreads();
#pragma unroll
  for (int i = 0; i < 64; i += 4)
    dst[(size_t)(nb + ty + i) * K + kb + tx] = tile[tx][ty + i];
}

// ---------- small conversions + Ww fused into WbfT2 rows 1024..1151 ----------
__global__ __launch_bounds__(256) void cvt_small(
    const void* __restrict__ Ww, const void* __restrict__ bw,
    const void* __restrict__ bi, const void* __restrict__ bb,
    const void* __restrict__ bf_, const void* __restrict__ bo,
    bf16* __restrict__ WbfT2, bf16* __restrict__ bbf2,
    bf16* __restrict__ biC, bf16* __restrict__ boC,
    const int* __restrict__ flagp)
{
  const int f32 = *flagp;
  int i = blockIdx.x * 256 + threadIdx.x;  // grid 512 -> 131072 threads
  if (i < 131072) {
    int r = i >> 10, k = i & 1023;
    bf16 v = (r < 8) ? ld_bf16(Ww, (size_t)k * 8 + r, f32) : f2b(0.f);
    WbfT2[(size_t)(1024 + r) * 1024 + k] = v;
  }
  if (i < 128) bbf2[1024 + i] = (i < 8) ? ld_bf16(bw, i, f32) : f2b(0.f);
  if (i < 1024) biC[i] = ld_bf16(bi, i, f32);
  if (i < 512)  bbf2[i] = ld_bf16(bb, i, f32);
  if (i < 512)  bbf2[512 + i] = ld_bf16(bf_, i, f32);
  if (i < 4096) boC[i] = ld_bf16(bo, i, f32);
}

// ---------- MFMA GEMM core: C = A(MxK) * BT(NxK)^T + bias [+resid] ----------
// 64x128 tile, BK=64, 4 waves (2x2), single-buffered 2-barrier loop (R5 best).
// Epilogue: LDS-staged, and the store mapping keeps a SINGLE INSTRUCTION's
// lanes contiguous: row=(tid>>4)+16*i, col=(tid&15)*4 -> 16 lanes cover 64
// consecutive cols (256B fp32 / 128B bf16 segments). R7's (tid&3)*16 mapping
// put each lane's 16B a 64B-stride apart -> partial-line writes, 2x WRITE
// amplification (274MB vs 134MB output) + RFO fetches. Counters convicted it.
template <int BM, int BN>
__device__ __forceinline__ void gemm_core(
    const void* __restrict__ A,      // M x K (bf16, or fp32 if *aF32)
    const bf16* __restrict__ BT,     // N x K
    const bf16* __restrict__ bias,   // N
    const void* __restrict__ resid,  // M x N (nullable; dtype follows rF32)
    void* __restrict__ C,            // M x N (bf16, or fp32 if *cF32)
    const int* __restrict__ aF32, const int* __restrict__ rF32,
    const int* __restrict__ cF32,
    int M, int N, int K, int clip_cols)
{
  static_assert(BM == 64 && BN == 128, "epilogue assumes 64x128");
  constexpr int FM = BM / 32;  // 2
  constexpr int FN = BN / 32;  // 4
  __shared__ alignas(16) char smem[(BM + BN) * 64 * 2];  // 24576 B
  bf16* As = (bf16*)smem;            // BM*64
  bf16* Bs = (bf16*)smem + BM * 64;  // BN*64
  const int af32 = aF32 ? *aF32 : 0;
  const int rf32 = rF32 ? *rF32 : 0;
  const int cf32 = cF32 ? *cF32 : 0;
  const int tid  = threadIdx.x;
  const int wave = tid >> 6;
  const int lane = tid & 63;
  const int m0 = blockIdx.x * BM;
  const int n0 = blockIdx.y * BN;
  const int wm = (wave >> 1) * (BM / 2);
  const int wn = (wave & 1) * (BN / 2);
  const int lm = lane & 15;
  const int lk = (lane >> 4) * 8;

  float4_t acc[FM][FN];
#pragma unroll
  for (int i = 0; i < FM; i++)
#pragma unroll
    for (int j = 0; j < FN; j++) acc[i][j] = (float4_t){0.f, 0.f, 0.f, 0.f};

  for (int k0 = 0; k0 < K; k0 += 64) {
    // B tile: BN rows x 64 cols, async direct-to-LDS (always bf16)
#pragma unroll
    for (int i = 0; i < BN / 32; i++) {
      int V = tid + 256 * i;
      int row = V >> 3;
      int kc  = (V & 7) * 8;
      gload_lds16(BT + (size_t)(n0 + row) * K + k0 + kc, Bs + (size_t)V * 8);
    }
    // A tile: BM rows x 64 cols
#pragma unroll
    for (int i = 0; i < BM / 32; i++) {
      int V = tid + 256 * i;
      int row = V >> 3;
      int kc  = (V & 7) * 8;
      if (af32) {
        const float* ap = (const float*)A + (size_t)(m0 + row) * K + k0 + kc;
        float4_t f0 = *(const float4_t*)ap;
        float4_t f1 = *(const float4_t*)(ap + 4);
        short8 v;
        v[0] = f2b_bits(f0[0]); v[1] = f2b_bits(f0[1]);
        v[2] = f2b_bits(f0[2]); v[3] = f2b_bits(f0[3]);
        v[4] = f2b_bits(f1[0]); v[5] = f2b_bits(f1[1]);
        v[6] = f2b_bits(f1[2]); v[7] = f2b_bits(f1[3]);
        *(short8*)(As + (size_t)V * 8) = v;
      } else {
        gload_lds16((const bf16*)A + (size_t)(m0 + row) * K + k0 + kc,
                    As + (size_t)V * 8);
      }
    }
    __syncthreads();
#pragma unroll
    for (int kk = 0; kk < 64; kk += 32) {
      short8 af[FM], bfr[FN];
#pragma unroll
      for (int mi = 0; mi < FM; mi++)
        af[mi] = *(const short8*)(As + (wm + mi * 16 + lm) * 64 + kk + lk);
#pragma unroll
      for (int ni = 0; ni < FN; ni++)
        bfr[ni] = *(const short8*)(Bs + (wn + ni * 16 + lm) * 64 + kk + lk);
#pragma unroll
      for (int mi = 0; mi < FM; mi++)
#pragma unroll
        for (int ni = 0; ni < FN; ni++)
          acc[mi][ni] = __builtin_amdgcn_mfma_f32_16x16x32_bf16(
              af[mi], bfr[ni], acc[mi][ni], 0, 0, 0);
    }
    __syncthreads();
  }

  // ---- coalesced epilogue: per 64-col half, stage fp32 tile in LDS ----
  // MFMA C/D layout: col=lane&15, row=(lane>>4)*4+r.
  float* EP = (float*)smem;           // [64][68] fp32 = 17408 B <= 24576
  const int ep_c = (tid & 15) * 4;    // 0..60: 16 lanes = 64 consecutive cols
#pragma unroll
  for (int h = 0; h < 2; h++) {
    if ((wn >> 6) == h) {             // this wave's cols are in half h
#pragma unroll
      for (int mi = 0; mi < FM; mi++)
#pragma unroll
        for (int ni = 0; ni < FN; ni++) {
          int cl = (wn - h * 64) + ni * 16 + lm;  // 0..63
#pragma unroll
          for (int r = 0; r < 4; r++) {
            int rw = wm + mi * 16 + (lane >> 4) * 4 + r;  // 0..63
            EP[rw * 68 + cl] = acc[mi][ni][r];
          }
        }
    }
    __syncthreads();
#pragma unroll
    for (int i = 0; i < 4; i++) {
      int rw  = (tid >> 4) + 16 * i;  // 0..63
      int gr  = m0 + rw;
      int col = n0 + h * 64 + ep_c;
      size_t idx = (size_t)gr * N + col;
      float4_t v = *(const float4_t*)(EP + rw * 68 + ep_c);
      float o[4];
#pragma unroll
      for (int j = 0; j < 4; j++) {
        float t = v[j] + __bfloat162float(bias[col + j]);
        if (col + j < clip_cols) t = fminf(fmaxf(t, -10.f), 10.f);
        o[j] = t;
      }
      if (resid) {
        if (rf32) {
          float4_t rv = *(const float4_t*)((const float*)resid + idx);
#pragma unroll
          for (int j = 0; j < 4; j++) o[j] += rv[j];
        } else {
          short4_t rv = *(const short4_t*)((const bf16*)resid + idx);
#pragma unroll
          for (int j = 0; j < 4; j++) {
            bf16 hb; short sb = rv[j]; __builtin_memcpy(&hb, &sb, 2);
            o[j] += __bfloat162float(hb);
          }
        }
      }
      if (cf32) {
        *(float4_t*)((float*)C + idx) = (float4_t){o[0], o[1], o[2], o[3]};
      } else {
        short4_t pv;
#pragma unroll
        for (int j = 0; j < 4; j++) pv[j] = f2b_bits(o[j]);
        *(short4_t*)((bf16*)C + idx) = pv;
      }
    }
    __syncthreads();  // EP reads done before next half overwrites
  }
}

// distinct names -> per-GEMM rocprof attribution
__global__ __launch_bounds__(256) void gemm_x(
    const void* A, const bf16* BT, const bf16* bias, const void* resid,
    void* C, const int* aF32, const int* rF32, const int* cF32,
    int M, int N, int K, int clip_cols) {
  gemm_core<64, 128>(A, BT, bias, resid, C, aF32, rF32, cF32, M, N, K, clip_cols);
}
__global__ __launch_bounds__(256) void gemm_h(
    const void* A, const bf16* BT, const bf16* bias, const void* resid,
    void* C, const int* aF32, const int* rF32, const int* cF32,
    int M, int N, int K, int clip_cols) {
  gemm_core<64, 128>(A, BT, bias, resid, C, aF32, rF32, cF32, M, N, K, clip_cols);
}
__global__ __launch_bounds__(256) void gemm_o(
    const void* A, const bf16* BT, const bf16* bias, const void* resid,
    void* C, const int* aF32, const int* rF32, const int* cF32,
    int M, int N, int K, int clip_cols) {
  gemm_core<64, 128>(A, BT, bias, resid, C, aF32, rF32, cF32, M, N, K, clip_cols);
}

// ---------- per-token: softmax over fused logit cols + temporal mix + agg ----
__global__ __launch_bounds__(128) void build_combined(
    const bf16* __restrict__ bcfs,  // 8192 x 1152: 0..511 bc, 512..1023 fs, 1024..1031 logits
    bf16* __restrict__ comb)        // 8192 x 128
{
  int t = blockIdx.x;
  int tid = threadIdx.x;  // 0..127
  int tl = t & 2047;      // t_local within batch (T=2048)
  __shared__ float lg[8];
  __shared__ float w[8];
  if (tid < 8) lg[tid] = __bfloat162float(bcfs[(size_t)t * 1152 + 1024 + tid]);
  __syncthreads();
  if (tid < 8) {
    float mx = lg[0];
#pragma unroll
    for (int i = 1; i < 8; i++) mx = fmaxf(mx, lg[i]);
    float den = 0.f;
#pragma unroll
    for (int i = 0; i < 8; i++) den += expf(lg[i] - mx);
    w[tid] = expf(lg[tid] - mx) / den;
  }
  __syncthreads();
  float s = 0.f;
  if (tid < 64) {
    int d = tid;
    const bf16* bc = bcfs + (size_t)t * 1152;
    size_t tp = (tl == 0) ? (size_t)t : (size_t)t - 1;
    const bf16* bp = bcfs + tp * 1152;
#pragma unroll
    for (int p = 0; p < 8; p++) {
      float cur = __bfloat162float(bc[p * 64 + d]);
      float v = (tl == 0) ? cur : (0.9f * cur + 0.1f * __bfloat162float(bp[p * 64 + d]));
      s += w[p] * v;
    }
  } else {
    int d = tid - 64;
    const bf16* fsrow = bcfs + (size_t)t * 1152 + 512;
#pragma unroll
    for (int p = 0; p < 8; p++) s += w[p] * __bfloat162float(fsrow[p * 64 + d]);
  }
  comb[(size_t)t * 128 + tid] = __float2bfloat16(s);
}

extern "C" void kernel_launch(void* const* d_in, const int* in_sizes, int n_in,
                              void* d_out, int out_size, void* d_ws, size_t ws_size,
                              hipStream_t stream) {
  (void)in_sizes; (void)n_in; (void)out_size; (void)ws_size;
  const void* x   = d_in[0];   // 8192 x 4096
  const void* Wi  = d_in[1];   // 4096 x 1024
  const void* bi  = d_in[2];   // 1024
  const void* Wb  = d_in[3];   // 1024 x 512
  const void* bb  = d_in[4];   // 512
  const void* Wf  = d_in[5];   // 1024 x 512
  const void* bfv = d_in[6];   // 512
  const void* Ww  = d_in[9];   // 1024 x 8
  const void* bw  = d_in[10];  // 8
  const void* Wo  = d_in[17];  // 128 x 4096
  const void* bo  = d_in[18];  // 4096

  char* ws = (char*)d_ws;
  bf16*  h_bot = (bf16*)(ws + 0);          // 16,777,216 (comb aliases after GEMM2)
  bf16*  comb  = (bf16*)(ws + 0);          // 2,097,152 alias: h_bot dead after GEMM2
  bf16*  bcfs  = (bf16*)(ws + 16777216);   // 8192x1152x2 = 18,874,368
  bf16*  WiT   = (bf16*)(ws + 35651584);   //  8,388,608
  bf16*  WbfT2 = (bf16*)(ws + 44040192);   // 1152x1024x2 = 2,359,296
  bf16*  WoT   = (bf16*)(ws + 46399488);   //  1,048,576
  bf16*  biC   = (bf16*)(ws + 47448064);   //      2,048
  bf16*  bbf2C = (bf16*)(ws + 47450112);   //      2,304
  bf16*  boC   = (bf16*)(ws + 47452416);   //      8,192
  int*   flag  = (int*)(ws + 47460608);    //          4

  detect_dtype<<<1, 64, 0, stream>>>(bi, flag);

  transpose_all<<<1408, 256, 0, stream>>>(Wi, Wb, Wf, Wo, WiT, WbfT2, WoT, flag);
  cvt_small<<<512, 256, 0, stream>>>(Ww, bw, bi, bb, bfv, bo,
                                     WbfT2, bbf2C, biC, boC, flag);

  // GEMM1: h_bot = x @ Wi + bi  (A = x fp32-flagged; 64x128, grid 1024)
  gemm_x<<<dim3(128, 8), 256, 0, stream>>>(
      x, WiT, biC, nullptr, h_bot, flag, nullptr, nullptr,
      8192, 1024, 4096, 0);
  // GEMM2: [bc | fs | logits | pad] = h_bot @ [Wb|Wf|Ww|0] + [bb|bf|bw|0]
  gemm_h<<<dim3(128, 9), 256, 0, stream>>>(
      h_bot, WbfT2, bbf2C, nullptr, bcfs, nullptr, nullptr, nullptr,
      8192, 1152, 1024, 512);
  build_combined<<<8192, 128, 0, stream>>>(bcfs, comb);
  // GEMM3: out = x + comb @ Wo + bo — resid = x (flagged), OUTPUT dtype follows flag
  gemm_o<<<dim3(128, 32), 256, 0, stream>>>(
      comb, WoT, boC, x, d_out, nullptr, flag, flag,
      8192, 4096, 128, 0);
}